// Round 1
// baseline (797.338 us; speedup 1.0000x reference)
//
#include <hip/hip_runtime.h>
#include <stdint.h>

#define NB 32
#define SEQ 128
#define EMB 128
#define NSTEP 127   // S-1 scan steps
#define QNn 4
#define SNn 10

__device__ __forceinline__ float ftanh(float x) {
  float e = __expf(2.f * x);
  return 1.f - 2.f / (e + 1.f);
}
__device__ __forceinline__ float fsig(float x) {
  return 1.f / (1.f + __expf(-x));
}

// Chunked row-matmul: out(r,e) = emit(r, e, bias[e] + dot(Xl[r,:], W[e,:])), K=128, NE=128.
// W staged in LDS 32 e-rows at a time, pad 129 (conflict-free: bank = (e+k)%32).
template <typename EmitFn>
__device__ __forceinline__ void mm_rows_k128(const float* __restrict__ W,
                                             const float* __restrict__ bias,
                                             const float* Xl, int nrows,
                                             float* Wc, EmitFn emit)
{
  const int tid = threadIdx.x;
  const int elo = tid & 31, rb = tid >> 5;
  for (int c = 0; c < 4; ++c) {
    __syncthreads();
    #pragma unroll
    for (int m = 0; m < 4; ++m) {
      int f4 = tid + 256 * m;
      int row = f4 >> 5, k4 = (f4 & 31) << 2;
      const float4 w = *(const float4*)(W + (c * 32 + row) * 128 + k4);
      float* d = Wc + row * 129 + k4;
      d[0] = w.x; d[1] = w.y; d[2] = w.z; d[3] = w.w;
    }
    __syncthreads();
    const int e = c * 32 + elo;
    const float be = bias[e];
    const float* wr = Wc + elo * 129;
    for (int r = rb; r < nrows; r += 8) {
      const float* xr = Xl + r * 128;
      float acc = be;
      #pragma unroll 8
      for (int k = 0; k < 128; ++k) acc = fmaf(wr[k], xr[k], acc);
      emit(r, e, acc);
    }
  }
  __syncthreads();
}

// ---------------------------------------------------------------------------
// K1: per (b, block-of-4 t's): GNN aggregation -> emb_qt -> LSTM gate -> h_t,
// plus c_hist precompute Cq[b,t] = tanh(h_t @ Wq.T + bq) @ w_k.
// ---------------------------------------------------------------------------
__global__ __launch_bounds__(256, 2) void k_agg(
    const int* __restrict__ question, const int* __restrict__ response,
    const int* __restrict__ maskp, const int* __restrict__ q_neighbors,
    const int* __restrict__ s_neighbors, const float* __restrict__ emb_q,
    const float* __restrict__ emb_s, const float* __restrict__ emb_r,
    const float* __restrict__ W_ih, const float* __restrict__ b_ih,
    const float* __restrict__ b_hh, const float* __restrict__ W_agg,
    const float* __restrict__ b_agg, const float* __restrict__ W_last,
    const float* __restrict__ b_last, const float* __restrict__ W_query,
    const float* __restrict__ b_query, const float* __restrict__ w_W,
    float* __restrict__ Hfull, float* __restrict__ Cq)
{
  __shared__ float Wc[4128];    // [32][129] (K=128) or [16][257] (K=256)
  __shared__ float Xbig[5120];  // phase1: 40x128 level-2 input; phase2: E11 @0, gates @2048
  __shared__ float X1[2048];    // phase1: 16x128 (m2_orig+e1_orig); phase2: e0in@0, hbuf@512, xcat@1024
  __shared__ float M2N[2048];   // sum_j tanh(level-2 out); later mean+e1_1
  __shared__ float m1o[512];    // mean(e1_orig); later reduction scratch
  __shared__ float m11[512];    // mean(e1_1)
  __shared__ float m12[512];    // mean(e1_2)
  __shared__ float e0v[512];    // evolving e0
  __shared__ int n1s[4];
  __shared__ int n2s[40];
  __shared__ int n3s[160];
  __shared__ int qts[4], rts[4], mts[4];

  const int tid = threadIdx.x;
  const int b = blockIdx.x >> 5;
  const int tblk = blockIdx.x & 31;
  const int t0 = tblk * 4;
  const int nt = min(4, NSTEP - t0);   // 127 = 31*4 + 3 -> last block nt=3
  if (nt <= 0) return;

  // -------- phase 1: per-t gathers + 40-row level-2 matmul --------
  for (int tt = 0; tt < nt; ++tt) {
    const int t = t0 + tt;
    if (tid == 0) {
      qts[tt] = question[b * SEQ + t];
      rts[tt] = response[b * SEQ + t];
      mts[tt] = maskp[b * SEQ + t];
    }
    __syncthreads();
    const int qt = qts[tt];
    if (tid < 4) n1s[tid] = q_neighbors[qt * QNn + tid];
    __syncthreads();
    if (tid < 40) n2s[tid] = s_neighbors[n1s[tid / 10] * SNn + tid % 10];
    __syncthreads();
    if (tid < 160) n3s[tid] = q_neighbors[n2s[tid >> 2] * QNn + (tid & 3)];
    // X1 row (tt*4+i) = mean_j(e2_orig) + e1_orig ; zero M2N rows
    for (int j = tid; j < 512; j += 256) {
      int i = j >> 7, e = j & 127;
      float s = 0.f;
      #pragma unroll
      for (int jj = 0; jj < 10; ++jj) s += emb_q[(size_t)n2s[i * 10 + jj] * EMB + e];
      X1[(tt * 4 + i) * EMB + e] = 0.1f * s + emb_s[n1s[i] * EMB + e];
      M2N[(tt * 4 + i) * EMB + e] = 0.f;
    }
    if (tid < 128) {
      float s = 0.f;
      #pragma unroll
      for (int i = 0; i < 4; ++i) s += emb_s[n1s[i] * EMB + tid];
      m1o[tt * EMB + tid] = 0.25f * s;
    }
    __syncthreads();
    // Xbig = e2_orig + mean_k(e3)
    for (int j = tid; j < 5120; j += 256) {
      int r = j >> 7, e = j & 127;
      float s = 0.f;
      #pragma unroll
      for (int k = 0; k < 4; ++k) s += emb_s[n3s[r * 4 + k] * EMB + e];
      Xbig[j] = emb_q[(size_t)n2s[r] * EMB + e] + 0.25f * s;
    }
    // 40-row matmul with W_agg[2]; accumulate sum_j tanh into M2N
    const float* W2 = W_agg + 2 * EMB * EMB;
    const int elo = tid & 31, rb = tid >> 5;
    for (int c = 0; c < 4; ++c) {
      __syncthreads();
      #pragma unroll
      for (int m = 0; m < 4; ++m) {
        int f4 = tid + 256 * m;
        int row = f4 >> 5, k4 = (f4 & 31) << 2;
        const float4 w = *(const float4*)(W2 + (c * 32 + row) * 128 + k4);
        float* d = Wc + row * 129 + k4;
        d[0] = w.x; d[1] = w.y; d[2] = w.z; d[3] = w.w;
      }
      __syncthreads();
      const int e = c * 32 + elo;
      const float be = b_agg[2 * EMB + e];
      float a0 = be, a1 = be, a2 = be, a3 = be, a4 = be;
      const float* wr = Wc + elo * 129;
      const float* x0 = Xbig + (rb * 5 + 0) * 128;
      const float* x1 = Xbig + (rb * 5 + 1) * 128;
      const float* x2 = Xbig + (rb * 5 + 2) * 128;
      const float* x3 = Xbig + (rb * 5 + 3) * 128;
      const float* x4 = Xbig + (rb * 5 + 4) * 128;
      #pragma unroll 4
      for (int k = 0; k < 128; ++k) {
        float w = wr[k];
        a0 = fmaf(w, x0[k], a0); a1 = fmaf(w, x1[k], a1);
        a2 = fmaf(w, x2[k], a2); a3 = fmaf(w, x3[k], a3);
        a4 = fmaf(w, x4[k], a4);
      }
      float part = ftanh(a0) + ftanh(a1) + ftanh(a2) + ftanh(a3) + ftanh(a4);
      atomicAdd(&M2N[(tt * 4 + (rb >> 1)) * EMB + e], part);  // rows rb*5.. share i=rb/2
    }
    __syncthreads();
  }

  // -------- phase 2: batched small matmuls across the nt timesteps --------
  const int nr16 = nt * 4;
  float* E11 = Xbig;
  float* gates = Xbig + 2048;
  float* e0in = X1;          // X1 input rows dead after B1/B2
  float* hbuf = X1 + 512;
  float* xcat = X1 + 1024;

  for (int j = tid; j < 512; j += 256) { m11[j] = 0.f; m12[j] = 0.f; }

  // B1: e1_1 = tanh(X1 @ W1.T + b1); accumulate mean_i into m11
  mm_rows_k128(W_agg + EMB * EMB, b_agg + EMB, X1, nr16, Wc,
               [&](int r, int e, float acc) {
                 float v = ftanh(acc);
                 E11[r * EMB + e] = v;
                 atomicAdd(&m11[(r >> 2) * EMB + e], 0.25f * v);
               });
  // B2: e1_2 = tanh((mean_j(e2_1) + e1_1) @ W1.T + b1); only mean_i needed
  for (int j = tid; j < nr16 * EMB; j += 256) M2N[j] = M2N[j] * 0.1f + E11[j];
  mm_rows_k128(W_agg + EMB * EMB, b_agg + EMB, M2N, nr16, Wc,
               [&](int r, int e, float acc) {
                 atomicAdd(&m12[(r >> 2) * EMB + e], 0.25f * ftanh(acc));
               });
  // B3: e0_1 = tanh((m1o + emb_q[qt]) @ W0.T + b0)
  for (int j = tid; j < nt * EMB; j += 256) {
    int ttj = j >> 7, e = j & 127;
    e0in[j] = m1o[j] + emb_q[(size_t)qts[ttj] * EMB + e];
  }
  mm_rows_k128(W_agg, b_agg, e0in, nt, Wc,
               [&](int r, int e, float acc) { e0v[r * EMB + e] = ftanh(acc); });
  // B4: e0_2 = tanh((m11 + e0_1) @ W0.T + b0)
  for (int j = tid; j < nt * EMB; j += 256) e0in[j] = m11[j] + e0v[j];
  mm_rows_k128(W_agg, b_agg, e0in, nt, Wc,
               [&](int r, int e, float acc) { e0v[r * EMB + e] = ftanh(acc); });
  // B5: e0_3 = tanh((m12 + e0_2) @ W0.T + b0)
  for (int j = tid; j < nt * EMB; j += 256) e0in[j] = m12[j] + e0v[j];
  mm_rows_k128(W_agg, b_agg, e0in, nt, Wc,
               [&](int r, int e, float acc) { e0v[r * EMB + e] = ftanh(acc); });
  // B6: agg = tanh(e0_3 @ W_last.T + b_last); emb_qt = mask ? agg : emb_q[qt]
  mm_rows_k128(W_last, b_last, e0v, nt, Wc,
               [&](int r, int e, float acc) {
                 float agg = ftanh(acc);
                 xcat[r * 256 + e] = (mts[r] == 1) ? agg
                                   : emb_q[(size_t)qts[r] * EMB + e];
               });
  for (int j = tid; j < nt * EMB; j += 256) {
    int ttj = j >> 7, e = j & 127;
    xcat[ttj * 256 + 128 + e] = emb_r[rts[ttj] * EMB + e];
  }
  for (int j = tid; j < nt * 512; j += 256) {
    int e = j & 511;
    gates[j] = b_ih[e] + b_hh[e];
  }
  __syncthreads();
  // B7: gates += xcat @ W_ih.T   (K=256, NE=512, 16 out-rows/chunk, 4-way k-split)
  {
    const int elo16 = tid & 15;
    const int rq = tid >> 4;
    const int ttq = rq & 3;
    const int kh = rq >> 2;
    for (int c = 0; c < 32; ++c) {
      #pragma unroll
      for (int m = 0; m < 4; ++m) {
        int f4 = tid + 256 * m;
        int row = f4 >> 6, k4 = (f4 & 63) << 2;
        const float4 w = *(const float4*)(W_ih + (size_t)(c * 16 + row) * 256 + k4);
        float* d = Wc + row * 257 + k4;
        d[0] = w.x; d[1] = w.y; d[2] = w.z; d[3] = w.w;
      }
      __syncthreads();
      if (ttq < nt) {
        float acc = 0.f;
        const float* wr = Wc + elo16 * 257 + kh * 64;
        const float* xr = xcat + ttq * 256 + kh * 64;
        #pragma unroll 8
        for (int k = 0; k < 64; ++k) acc = fmaf(wr[k], xr[k], acc);
        atomicAdd(&gates[ttq * 512 + c * 16 + elo16], acc);
      }
      __syncthreads();
    }
  }
  // B8: h = sig(go) * tanh(sig(gi) * tanh(gg))
  for (int j = tid; j < nt * EMB; j += 256) {
    int ttj = j >> 7, e = j & 127;
    float gi = gates[ttj * 512 + e];
    float gg = gates[ttj * 512 + 256 + e];
    float go = gates[ttj * 512 + 384 + e];
    float h = fsig(go) * ftanh(fsig(gi) * ftanh(gg));
    hbuf[j] = h;
    Hfull[((size_t)b * NSTEP + (t0 + ttj)) * EMB + e] = h;
  }
  __syncthreads();
  // B9: Cq[b,t] = tanh(h @ Wq.T + bq) @ w_k
  mm_rows_k128(W_query, b_query, hbuf, nt, Wc,
               [&](int r, int e, float acc) { e0in[r * EMB + e] = ftanh(acc); });
  {
    float* red = m1o;  // dead; reuse as scratch (512 >= 256)
    for (int tt2 = 0; tt2 < nt; ++tt2) {
      red[tid] = (tid < 128) ? e0in[tt2 * EMB + tid] * w_W[EMB + tid] : 0.f;
      __syncthreads();
      #pragma unroll
      for (int s2 = 128; s2 > 0; s2 >>= 1) {
        if (tid < s2) red[tid] += red[tid + s2];
        __syncthreads();
      }
      if (tid == 0) Cq[b * NSTEP + t0 + tt2] = red[0];
      __syncthreads();
    }
  }
}

// ---------------------------------------------------------------------------
// K2: per (b,t): u = emb_q[q_next] + sum(emb_s[top-k cols]), match bitmask, n_sel
// ---------------------------------------------------------------------------
__global__ __launch_bounds__(128) void k_match(
    const int* __restrict__ question, const int* __restrict__ q_neighbors,
    const int* __restrict__ s_neighbors, const float* __restrict__ qs_table,
    const float* __restrict__ emb_q, const float* __restrict__ emb_s,
    float* __restrict__ Ufull, int* __restrict__ nsel,
    unsigned long long* __restrict__ mwords)
{
  __shared__ int cnt;
  __shared__ int cols[8];
  __shared__ int nq1[4];
  __shared__ int qr[40];
  __shared__ unsigned long long w0s[2];
  const int tid = threadIdx.x;
  const int bid = blockIdx.x;
  const int b = bid / NSTEP, t = bid % NSTEP;
  const int q_next = question[b * SEQ + t + 1];

  if (tid == 0) cnt = 0;
  if (tid < 4) nq1[tid] = q_neighbors[q_next * QNn + tid];
  __syncthreads();
  // collect nonzero cols of qs_table row (<=4 ones; order irrelevant for the sum)
  #pragma unroll
  for (int m = 0; m < 4; ++m) {
    int c = tid + 128 * m;
    float v = qs_table[(size_t)q_next * 512 + c];
    if (v > 0.f) {
      int p = atomicAdd(&cnt, 1);
      if (p < 8) cols[p] = c;
    }
  }
  if (tid < 40) qr[tid] = s_neighbors[nq1[tid / 10] * SNn + tid % 10];
  __syncthreads();
  const int nc = min(cnt, 4);
  // u
  {
    float ue = emb_q[(size_t)q_next * EMB + tid];
    for (int i = 0; i < nc; ++i) ue += emb_s[cols[i] * EMB + tid];
    Ufull[((size_t)b * NSTEP + t) * EMB + tid] = ue;
  }
  // matches: p = tid, match iff p < t && question[b,p] in qr
  bool pred = false;
  if (tid < t) {
    int qp = question[b * SEQ + tid];
    #pragma unroll 8
    for (int i = 0; i < 40; ++i) pred |= (qp == qr[i]);
  }
  unsigned long long bal = __ballot(pred);
  if ((tid & 63) == 0) w0s[tid >> 6] = bal;
  __syncthreads();
  if (tid == 0) {
    unsigned long long a0 = w0s[0], a1 = w0s[1];
    mwords[((size_t)b * NSTEP + t) * 2 + 0] = a0;
    mwords[((size_t)b * NSTEP + t) * 2 + 1] = a1;
    nsel[b * NSTEP + t] = __popcll(a0) + __popcll(a1);
  }
}

__device__ __forceinline__ float bsum128(float v, float* red) {
  const int tid = threadIdx.x;
  __syncthreads();
  red[tid] = v;
  __syncthreads();
  #pragma unroll
  for (int s = 64; s > 0; s >>= 1) {
    if (tid < s) red[tid] += red[tid + s];
    __syncthreads();
  }
  return red[0];
}
__device__ __forceinline__ float bmax128(float v, float* red) {
  const int tid = threadIdx.x;
  __syncthreads();
  red[tid] = v;
  __syncthreads();
  #pragma unroll
  for (int s = 64; s > 0; s >>= 1) {
    if (tid < s) red[tid] = fmaxf(red[tid], red[tid + s]);
    __syncthreads();
  }
  return red[0];
}

// ---------------------------------------------------------------------------
// K3: collapsed attention (a[q] cancels; see analysis), y -> out
// ---------------------------------------------------------------------------
__global__ __launch_bounds__(128) void k_attn(
    const float* __restrict__ b_query, const float* __restrict__ w_W,
    const float* __restrict__ Hfull, const float* __restrict__ Cq,
    const float* __restrict__ Ufull, const int* __restrict__ nsel,
    const unsigned long long* __restrict__ mwords, float* __restrict__ out)
{
  __shared__ float red[128];
  __shared__ float us[128];
  const int tid = threadIdx.x;
  const int bid = blockIdx.x;
  const int b = bid / NSTEP, t = bid % NSTEP;
  const size_t bt = (size_t)b * NSTEP + t;

  float c_pad = bsum128(ftanh(b_query[tid]) * w_W[EMB + tid], red);
  const int nown = nsel[bt];
  float Pmax = bmax128((tid < NB) ? (float)nsel[(size_t)tid * NSTEP + t] : 0.f, red);
  float P = Pmax - (float)nown;

  us[tid] = Ufull[bt * EMB + tid];
  const unsigned long long w0 = mwords[bt * 2 + 0];
  const unsigned long long w1 = mwords[bt * 2 + 1];
  const bool matched = (tid < 64) ? ((w0 >> tid) & 1ull)
                                  : ((w1 >> (tid - 64)) & 1ull);
  const float c_cur = Cq[bt];
  float Cp = 0.f;
  if (matched) Cp = (tid == 0) ? c_pad : Cq[(size_t)b * NSTEP + tid];
  float Mh = bmax128(matched ? Cp : -3.0e38f, red);
  float M = fmaxf(fmaxf(Mh, c_cur), c_pad);
  float wgt = matched ? __expf(Cp - M) : 0.f;
  float Sexp = bsum128(wgt, red);
  float dotp = 0.f;
  if (matched && tid >= 1) {  // p=0 history row is zeros -> dot 0
    const float* hp = Hfull + ((size_t)b * NSTEP + tid) * EMB;
    float s = 0.f;
    for (int e = 0; e < 128; ++e) s = fmaf(us[e], hp[e], s);
    dotp = s;
  }
  float Snum = bsum128(wgt * dotp, red);
  float gc = bsum128(us[tid] * Hfull[bt * EMB + tid], red);
  float Ec = __expf(c_cur - M), Ep = __expf(c_pad - M);
  float D = Sexp + Ec + P * Ep;
  float numt = Snum + Ec * gc;
  if (tid == 0) {
    out[b * SEQ + t + 1] = fsig(numt / D);
    if (t == 0) out[b * SEQ] = 0.5f;
  }
}

extern "C" void kernel_launch(void* const* d_in, const int* in_sizes, int n_in,
                              void* d_out, int out_size, void* d_ws, size_t ws_size,
                              hipStream_t stream) {
  const int* question    = (const int*)d_in[0];
  const int* response    = (const int*)d_in[1];
  const int* maskp       = (const int*)d_in[2];
  const int* q_neighbors = (const int*)d_in[3];
  const int* s_neighbors = (const int*)d_in[4];
  const float* qs_table  = (const float*)d_in[5];
  const float* emb_q     = (const float*)d_in[6];
  const float* emb_s     = (const float*)d_in[7];
  const float* emb_r     = (const float*)d_in[8];
  const float* W_ih      = (const float*)d_in[9];
  const float* b_ih      = (const float*)d_in[10];
  const float* b_hh      = (const float*)d_in[11];
  const float* W_agg     = (const float*)d_in[12];
  const float* b_agg     = (const float*)d_in[13];
  const float* W_last    = (const float*)d_in[14];
  const float* b_last    = (const float*)d_in[15];
  const float* W_query   = (const float*)d_in[16];
  const float* b_query   = (const float*)d_in[17];
  // d_in[18] W_key, d_in[19] b_key, d_in[21] b_W: provably no effect (a[q] cancels)
  const float* w_W       = (const float*)d_in[20];
  float* out = (float*)d_out;

  float* Hfull = (float*)d_ws;                         // NB*NSTEP*EMB
  float* Ufull = Hfull + (size_t)NB * NSTEP * EMB;     // NB*NSTEP*EMB
  float* Cq    = Ufull + (size_t)NB * NSTEP * EMB;     // NB*NSTEP
  int*   nselp = (int*)(Cq + NB * NSTEP);              // NB*NSTEP
  unsigned long long* mwords =
      (unsigned long long*)(((uintptr_t)(nselp + NB * NSTEP) + 15) & ~(uintptr_t)15);

  k_agg<<<dim3(NB * 32), dim3(256), 0, stream>>>(
      question, response, maskp, q_neighbors, s_neighbors, emb_q, emb_s, emb_r,
      W_ih, b_ih, b_hh, W_agg, b_agg, W_last, b_last, W_query, b_query, w_W,
      Hfull, Cq);
  k_match<<<dim3(NB * NSTEP), dim3(128), 0, stream>>>(
      question, q_neighbors, s_neighbors, qs_table, emb_q, emb_s,
      Ufull, nselp, mwords);
  k_attn<<<dim3(NB * NSTEP), dim3(128), 0, stream>>>(
      b_query, w_W, Hfull, Cq, Ufull, nselp, mwords, out);
}

// Round 2
// 534.706 us; speedup vs baseline: 1.4912x; 1.4912x over previous
//
#include <hip/hip_runtime.h>
#include <stdint.h>

#define NB 32
#define SEQ 128
#define EMB 128
#define NSTEP 127
#define NS 512

__device__ __forceinline__ float ftanh(float x){ float e=__expf(2.f*x); return 1.f-2.f/(e+1.f); }
__device__ __forceinline__ float fsig(float x){ return 1.f/(1.f+__expf(-x)); }
__device__ __forceinline__ float4 ld4(const float* p){ return *(const float4*)p; }

// 16 rows x (K=128 -> NE=128). W row-major [128][128], staged [16][132] chunks
// (132*4 B row stride => 16B-aligned b128 reads, 2-way bank alias = free).
// Each thread: one (row r = tid>>4, e = c*16 + (tid&15)) full-K dot -> emit.
template <typename EmitFn>
__device__ __forceinline__ void mm16_k128(const float* __restrict__ W,
                                          const float* __restrict__ bias,
                                          const float* xin, float* Wc, EmitFn emit)
{
  const int tid = threadIdx.x;
  const int el = tid & 15, r = tid >> 4;
  for (int c = 0; c < 8; ++c) {
    __syncthreads();
    #pragma unroll
    for (int m = 0; m < 2; ++m) {
      int f = tid + 256*m;
      int row = f >> 5, col = (f & 31) << 2;
      float4 w = ld4(W + (size_t)(c*16+row)*128 + col);
      float* d = Wc + row*132 + col;
      d[0]=w.x; d[1]=w.y; d[2]=w.z; d[3]=w.w;
    }
    __syncthreads();
    const float4* wr = (const float4*)(Wc + el*132);
    const float4* xr = (const float4*)(xin + r*128);
    float acc = 0.f;
    #pragma unroll
    for (int k = 0; k < 32; ++k) {
      float4 w = wr[k], x = xr[k];
      acc = fmaf(w.x,x.x,fmaf(w.y,x.y,fmaf(w.z,x.z,fmaf(w.w,x.w,acc))));
    }
    emit(r, c*16+el, acc + bias[c*16+el]);
  }
  __syncthreads();
}

// nr<=4 rows x (K -> NE). Thread = (e = tid&15, r = (tid>>4)&3, kh = tid>>6).
// 4-way K-split, partials combined via LDS atomicAdd into bias-preloaded xout.
template <int K, int NE>
__device__ __forceinline__ void mm4(const float* __restrict__ W, const float* xin,
                                    int xstride, float* xout, float* Wc, int nrows)
{
  const int tid = threadIdx.x;
  const int el = tid & 15;
  const int rq = tid >> 4;
  const int r  = rq & 3;
  const int kh = rq >> 2;          // 0..3 (per-wave uniform)
  const int WS = K + 4;
  const int KS = K / 4;
  for (int c = 0; c < NE/16; ++c) {
    __syncthreads();
    #pragma unroll
    for (int m = 0; m < K/64; ++m) {
      int f = tid + 256*m;
      int row = f / (K/4), col = (f % (K/4)) << 2;
      float4 w = ld4(W + (size_t)(c*16+row)*K + col);
      float* d = Wc + row*WS + col;
      d[0]=w.x; d[1]=w.y; d[2]=w.z; d[3]=w.w;
    }
    __syncthreads();
    if (r < nrows) {
      const float4* wr = (const float4*)(Wc + el*WS + kh*KS);
      const float4* xr = (const float4*)(xin + r*xstride + kh*KS);
      float acc = 0.f;
      #pragma unroll
      for (int k = 0; k < KS/4; ++k) {
        float4 w = wr[k], x = xr[k];
        acc = fmaf(w.x,x.x,fmaf(w.y,x.y,fmaf(w.z,x.z,fmaf(w.w,x.w,acc))));
      }
      atomicAdd(&xout[r*NE + c*16 + el], acc);
    }
  }
  __syncthreads();
}

// ---------------------------------------------------------------------------
// P1: E1[s] = tanh((emb_s[s] + 0.1*sum_j emb_q[s_neighbors[s,j]]) @ W1.T + b1)
//     G1[s] += tanh per (s,j) row of level-2 aggregation (global atomics).
// ---------------------------------------------------------------------------
__global__ __launch_bounds__(256) void k_pre(
    const int* __restrict__ s_neighbors, const int* __restrict__ q_neighbors,
    const float* __restrict__ emb_q, const float* __restrict__ emb_s,
    const float* __restrict__ W_agg, const float* __restrict__ b_agg,
    float* __restrict__ E1, float* __restrict__ G1)
{
  __shared__ float Wc[2112];
  __shared__ float xin[2048];
  __shared__ int idx[160];
  __shared__ int n3[64];
  const int tid = threadIdx.x;
  const int blk = blockIdx.x;
  if (blk < 32) {
    const int s0 = blk*16;
    if (tid < 160) idx[tid] = s_neighbors[s0*10 + tid];
    __syncthreads();
    for (int f = tid; f < 512; f += 256) {
      int i = f >> 5, e4 = (f & 31) << 2;
      float4 a = ld4(emb_s + (size_t)(s0+i)*128 + e4);
      float sx=0,sy=0,sz=0,sw=0;
      #pragma unroll
      for (int jj = 0; jj < 10; ++jj) {
        float4 q = ld4(emb_q + (size_t)idx[i*10+jj]*128 + e4);
        sx+=q.x; sy+=q.y; sz+=q.z; sw+=q.w;
      }
      float* d = xin + i*128 + e4;
      d[0]=a.x+0.1f*sx; d[1]=a.y+0.1f*sy; d[2]=a.z+0.1f*sz; d[3]=a.w+0.1f*sw;
    }
    mm16_k128(W_agg + 16384, b_agg + 128, xin, Wc,
      [&](int r, int e, float acc){ E1[(size_t)(s0+r)*128 + e] = ftanh(acc); });
  } else {
    const int p0 = (blk-32)*16;   // 5120 (s,j) pairs, 320 blocks
    if (tid < 16) idx[tid] = s_neighbors[p0 + tid];   // n2
    __syncthreads();
    if (tid < 64) n3[tid] = q_neighbors[(size_t)idx[tid>>2]*4 + (tid&3)];
    __syncthreads();
    for (int f = tid; f < 512; f += 256) {
      int i = f >> 5, e4 = (f & 31) << 2;
      float4 a = ld4(emb_q + (size_t)idx[i]*128 + e4);
      float sx=0,sy=0,sz=0,sw=0;
      #pragma unroll
      for (int k = 0; k < 4; ++k) {
        float4 q = ld4(emb_s + (size_t)n3[i*4+k]*128 + e4);
        sx+=q.x; sy+=q.y; sz+=q.z; sw+=q.w;
      }
      float* d = xin + i*128 + e4;
      d[0]=a.x+0.25f*sx; d[1]=a.y+0.25f*sy; d[2]=a.z+0.25f*sz; d[3]=a.w+0.25f*sw;
    }
    mm16_k128(W_agg + 2*16384, b_agg + 256, xin, Wc,
      [&](int r, int e, float acc){
        atomicAdd(&G1[(size_t)((p0+r)/10)*128 + e], ftanh(acc)); });
  }
}

// P2: E2[s] = tanh((0.1*G1[s] + E1[s]) @ W1.T + b1)
__global__ __launch_bounds__(256) void k_pre2(
    const float* __restrict__ E1, const float* __restrict__ G1,
    const float* __restrict__ W_agg, const float* __restrict__ b_agg,
    float* __restrict__ E2)
{
  __shared__ float Wc[2112];
  __shared__ float xin[2048];
  const int tid = threadIdx.x;
  const int s0 = blockIdx.x*16;
  for (int f = tid; f < 2048; f += 256)
    xin[f] = 0.1f*G1[(size_t)s0*128 + f] + E1[(size_t)s0*128 + f];
  mm16_k128(W_agg + 16384, b_agg + 128, xin, Wc,
    [&](int r, int e, float acc){ E2[(size_t)(s0+r)*128 + e] = ftanh(acc); });
}

// ---------------------------------------------------------------------------
// K1: per (b, 4 t's): table-lookup aggregation chain + LSTM h + Cq
// ---------------------------------------------------------------------------
__global__ __launch_bounds__(256) void k_chain(
    const int* __restrict__ question, const int* __restrict__ response,
    const int* __restrict__ maskp, const int* __restrict__ q_neighbors,
    const float* __restrict__ emb_q, const float* __restrict__ emb_s,
    const float* __restrict__ emb_r,
    const float* __restrict__ W_ih, const float* __restrict__ b_ih,
    const float* __restrict__ b_hh,
    const float* __restrict__ W_agg, const float* __restrict__ b_agg,
    const float* __restrict__ W_last, const float* __restrict__ b_last,
    const float* __restrict__ W_query, const float* __restrict__ b_query,
    const float* __restrict__ w_W,
    const float* __restrict__ E1, const float* __restrict__ E2,
    float* __restrict__ Hfull, float* __restrict__ Cq)
{
  __shared__ float pool[7240];
  __shared__ int qts[4], rts[4], mts[4], n1s[16];
  __shared__ float cq[4];
  float* Wc = pool;            // 4160
  float* A  = pool + 4160;     // 512
  float* Bb = A + 512;         // 512
  float* M1 = Bb + 512;        // 512
  float* M2 = M1 + 512;        // 512
  float* xcat = M2 + 512;      // 1024
  float* gates = A;            // 2048 overlay of A..M2 (contiguous)
  float* hbuf = xcat;          // 512 overlay (xcat dead after W_ih)
  float* xC = A;               // 512 overlay (gates dead after h)

  const int tid = threadIdx.x;
  const int b = blockIdx.x >> 5;
  const int chunk = blockIdx.x & 31;
  const int t0 = chunk*4;
  const int nt = min(4, NSTEP - t0);   // chunk 31 -> 3

  if (tid < nt) {
    qts[tid] = question[b*SEQ + t0 + tid];
    rts[tid] = response[b*SEQ + t0 + tid];
    mts[tid] = maskp[b*SEQ + t0 + tid];
  }
  __syncthreads();
  if (tid < nt*4) n1s[tid] = q_neighbors[(size_t)qts[tid>>2]*4 + (tid&3)];
  __syncthreads();
  // A = emb_q[qt] + 0.25*sum emb_s[n1]; M1 = 0.25*sum E1[n1]; M2 = 0.25*sum E2[n1]
  for (int f = tid; f < nt*32; f += 256) {
    int tt = f >> 5, e4 = (f & 31) << 2;
    const int* nn = n1s + tt*4;
    float4 a = ld4(emb_q + (size_t)qts[tt]*128 + e4);
    float s1x=0,s1y=0,s1z=0,s1w=0, s2x=0,s2y=0,s2z=0,s2w=0, s3x=0,s3y=0,s3z=0,s3w=0;
    #pragma unroll
    for (int i = 0; i < 4; ++i) {
      float4 q1 = ld4(emb_s + (size_t)nn[i]*128 + e4);
      float4 q2 = ld4(E1 + (size_t)nn[i]*128 + e4);
      float4 q3 = ld4(E2 + (size_t)nn[i]*128 + e4);
      s1x+=q1.x; s1y+=q1.y; s1z+=q1.z; s1w+=q1.w;
      s2x+=q2.x; s2y+=q2.y; s2z+=q2.z; s2w+=q2.w;
      s3x+=q3.x; s3y+=q3.y; s3z+=q3.z; s3w+=q3.w;
    }
    float* dA = A + tt*128 + e4;
    dA[0]=a.x+0.25f*s1x; dA[1]=a.y+0.25f*s1y; dA[2]=a.z+0.25f*s1z; dA[3]=a.w+0.25f*s1w;
    float* d1 = M1 + tt*128 + e4;
    d1[0]=0.25f*s2x; d1[1]=0.25f*s2y; d1[2]=0.25f*s2z; d1[3]=0.25f*s2w;
    float* d2 = M2 + tt*128 + e4;
    d2[0]=0.25f*s3x; d2[1]=0.25f*s3y; d2[2]=0.25f*s3z; d2[3]=0.25f*s3w;
  }
  for (int f = tid; f < nt*128; f += 256) Bb[f] = b_agg[f & 127];
  mm4<128,128>(W_agg, A, 128, Bb, Wc, nt);                 // e0_1 pre-act
  for (int f = tid; f < nt*128; f += 256) { A[f] = M1[f] + ftanh(Bb[f]); Bb[f] = b_agg[f&127]; }
  mm4<128,128>(W_agg, A, 128, Bb, Wc, nt);                 // e0_2
  for (int f = tid; f < nt*128; f += 256) { A[f] = M2[f] + ftanh(Bb[f]); Bb[f] = b_agg[f&127]; }
  mm4<128,128>(W_agg, A, 128, Bb, Wc, nt);                 // e0_3
  for (int f = tid; f < nt*128; f += 256) { A[f] = ftanh(Bb[f]); Bb[f] = b_last[f&127]; }
  mm4<128,128>(W_last, A, 128, Bb, Wc, nt);                // agg pre-act
  for (int f = tid; f < nt*128; f += 256) {
    int tt = f >> 7, e = f & 127;
    float agg = ftanh(Bb[f]);
    xcat[tt*256 + e] = (mts[tt]==1) ? agg : emb_q[(size_t)qts[tt]*128 + e];
    xcat[tt*256 + 128 + e] = emb_r[rts[tt]*128 + e];
  }
  __syncthreads();
  for (int f = tid; f < nt*512; f += 256) gates[f] = b_ih[f & 511] + b_hh[f & 511];
  mm4<256,512>(W_ih, xcat, 256, gates, Wc, nt);
  for (int f = tid; f < nt*128; f += 256) {
    int tt = f >> 7, e = f & 127;
    float gi = gates[tt*512 + e];
    float gg = gates[tt*512 + 256 + e];
    float go = gates[tt*512 + 384 + e];
    float h = fsig(go) * ftanh(fsig(gi)*ftanh(gg));
    hbuf[f] = h;
    Hfull[((size_t)b*NSTEP + t0 + tt)*128 + e] = h;
  }
  __syncthreads();
  for (int f = tid; f < nt*128; f += 256) xC[f] = b_query[f & 127];
  if (tid < 4) cq[tid] = 0.f;
  mm4<128,128>(W_query, hbuf, 128, xC, Wc, nt);
  for (int f = tid; f < nt*128; f += 256) {
    int tt = f >> 7, e = f & 127;
    atomicAdd(&cq[tt], ftanh(xC[f]) * w_W[128 + e]);
  }
  __syncthreads();
  if (tid < nt) Cq[b*NSTEP + t0 + tid] = cq[tid];
}

// ---------------------------------------------------------------------------
// K2: per (b,t): match bitmask + n_sel
// ---------------------------------------------------------------------------
__global__ __launch_bounds__(128) void k_match(
    const int* __restrict__ question, const int* __restrict__ q_neighbors,
    const int* __restrict__ s_neighbors,
    int* __restrict__ nsel, unsigned long long* __restrict__ mwords)
{
  __shared__ int nq1[4];
  __shared__ int qr[40];
  __shared__ unsigned long long w0s[2];
  const int tid = threadIdx.x;
  const int bid = blockIdx.x;
  const int b = bid / NSTEP, t = bid % NSTEP;
  const int q_next = question[b*SEQ + t + 1];

  if (tid < 4) nq1[tid] = q_neighbors[(size_t)q_next*4 + tid];
  __syncthreads();
  if (tid < 40) qr[tid] = s_neighbors[(size_t)nq1[tid/10]*10 + tid%10];
  __syncthreads();
  bool pred = false;
  if (tid < t) {
    int qp = question[b*SEQ + tid];
    #pragma unroll 8
    for (int i = 0; i < 40; ++i) pred |= (qp == qr[i]);
  }
  unsigned long long bal = __ballot(pred);
  if ((tid & 63) == 0) w0s[tid >> 6] = bal;
  __syncthreads();
  if (tid == 0) {
    unsigned long long a0 = w0s[0], a1 = w0s[1];
    mwords[((size_t)b*NSTEP + t)*2 + 0] = a0;
    mwords[((size_t)b*NSTEP + t)*2 + 1] = a1;
    nsel[b*NSTEP + t] = __popcll(a0) + __popcll(a1);
  }
}

__device__ __forceinline__ float bsum128(float v, float* red) {
  const int tid = threadIdx.x;
  __syncthreads();
  red[tid] = v;
  __syncthreads();
  #pragma unroll
  for (int s = 64; s > 0; s >>= 1) {
    if (tid < s) red[tid] += red[tid + s];
    __syncthreads();
  }
  return red[0];
}
__device__ __forceinline__ float bmax128(float v, float* red) {
  const int tid = threadIdx.x;
  __syncthreads();
  red[tid] = v;
  __syncthreads();
  #pragma unroll
  for (int s = 64; s > 0; s >>= 1) {
    if (tid < s) red[tid] = fmaxf(red[tid], red[tid + s]);
    __syncthreads();
  }
  return red[0];
}

// ---------------------------------------------------------------------------
// K3: collapsed attention (a[q] cancels), u computed inline, y -> out
// ---------------------------------------------------------------------------
__global__ __launch_bounds__(128) void k_attn(
    const int* __restrict__ question, const float* __restrict__ qs_table,
    const float* __restrict__ emb_q, const float* __restrict__ emb_s,
    const float* __restrict__ b_query, const float* __restrict__ w_W,
    const float* __restrict__ Hfull, const float* __restrict__ Cq,
    const int* __restrict__ nsel, const unsigned long long* __restrict__ mwords,
    float* __restrict__ out)
{
  __shared__ float red[128];
  __shared__ float us[128];
  __shared__ int cols[8];
  __shared__ int cnt;
  const int tid = threadIdx.x;
  const int bid = blockIdx.x;
  const int b = bid / NSTEP, t = bid % NSTEP;
  const size_t bt = (size_t)b*NSTEP + t;
  const int q_next = question[b*SEQ + t + 1];

  if (tid == 0) cnt = 0;
  __syncthreads();
  #pragma unroll
  for (int m = 0; m < 4; ++m) {
    int c = tid + 128*m;
    float v = qs_table[(size_t)q_next*NS + c];
    if (v > 0.f) {
      int p = atomicAdd(&cnt, 1);
      if (p < 8) cols[p] = c;
    }
  }
  __syncthreads();
  const int nc = min(cnt, 4);
  {
    float ue = emb_q[(size_t)q_next*EMB + tid];
    for (int i = 0; i < nc; ++i) ue += emb_s[(size_t)cols[i]*EMB + tid];
    us[tid] = ue;
  }
  float c_pad = bsum128(ftanh(b_query[tid]) * w_W[EMB + tid], red);
  const int nown = nsel[bt];
  float Pmax = bmax128((tid < NB) ? (float)nsel[(size_t)tid*NSTEP + t] : 0.f, red);
  float P = Pmax - (float)nown;

  const unsigned long long w0 = mwords[bt*2 + 0];
  const unsigned long long w1 = mwords[bt*2 + 1];
  const bool matched = (tid < 64) ? ((w0 >> tid) & 1ull)
                                  : ((w1 >> (tid - 64)) & 1ull);
  const float c_cur = Cq[bt];
  float Cp = 0.f;
  if (matched) Cp = (tid == 0) ? c_pad : Cq[(size_t)b*NSTEP + tid];
  float Mh = bmax128(matched ? Cp : -3.0e38f, red);
  float M = fmaxf(fmaxf(Mh, c_cur), c_pad);
  float wgt = matched ? __expf(Cp - M) : 0.f;
  float Sexp = bsum128(wgt, red);
  float dotp = 0.f;
  if (matched && tid >= 1) {  // p=0 history row is zeros
    const float* hp = Hfull + ((size_t)b*NSTEP + tid)*EMB;
    float s = 0.f;
    for (int e = 0; e < 128; ++e) s = fmaf(us[e], hp[e], s);
    dotp = s;
  }
  float Snum = bsum128(wgt * dotp, red);
  float gc = bsum128(us[tid] * Hfull[bt*EMB + tid], red);
  float Ec = __expf(c_cur - M), Ep = __expf(c_pad - M);
  float D = Sexp + Ec + P * Ep;
  float numt = Snum + Ec * gc;
  if (tid == 0) {
    out[b*SEQ + t + 1] = fsig(numt / D);
    if (t == 0) out[b*SEQ] = 0.5f;
  }
}

extern "C" void kernel_launch(void* const* d_in, const int* in_sizes, int n_in,
                              void* d_out, int out_size, void* d_ws, size_t ws_size,
                              hipStream_t stream) {
  const int* question    = (const int*)d_in[0];
  const int* response    = (const int*)d_in[1];
  const int* maskp       = (const int*)d_in[2];
  const int* q_neighbors = (const int*)d_in[3];
  const int* s_neighbors = (const int*)d_in[4];
  const float* qs_table  = (const float*)d_in[5];
  const float* emb_q     = (const float*)d_in[6];
  const float* emb_s     = (const float*)d_in[7];
  const float* emb_r     = (const float*)d_in[8];
  const float* W_ih      = (const float*)d_in[9];
  const float* b_ih      = (const float*)d_in[10];
  const float* b_hh      = (const float*)d_in[11];
  const float* W_agg     = (const float*)d_in[12];
  const float* b_agg     = (const float*)d_in[13];
  const float* W_last    = (const float*)d_in[14];
  const float* b_last    = (const float*)d_in[15];
  const float* W_query   = (const float*)d_in[16];
  const float* b_query   = (const float*)d_in[17];
  // d_in[18] W_key, d_in[19] b_key, d_in[21] b_W: no effect (a[q] cancels in softmax)
  const float* w_W       = (const float*)d_in[20];
  float* out = (float*)d_out;

  float* E1 = (float*)d_ws;                       // 512*128
  float* E2 = E1 + 65536;                         // 512*128
  float* G1 = E2 + 65536;                         // 512*128
  float* Hfull = G1 + 65536;                      // 32*127*128
  float* Cq = Hfull + (size_t)NB*NSTEP*EMB;       // 4064
  int* nselp = (int*)(Cq + NB*NSTEP);             // 4064
  unsigned long long* mwords =
      (unsigned long long*)(((uintptr_t)(nselp + NB*NSTEP) + 15) & ~(uintptr_t)15);

  hipMemsetAsync(G1, 0, 65536*sizeof(float), stream);
  k_pre<<<dim3(352), dim3(256), 0, stream>>>(
      s_neighbors, q_neighbors, emb_q, emb_s, W_agg, b_agg, E1, G1);
  k_pre2<<<dim3(32), dim3(256), 0, stream>>>(E1, G1, W_agg, b_agg, E2);
  k_chain<<<dim3(NB*32), dim3(256), 0, stream>>>(
      question, response, maskp, q_neighbors, emb_q, emb_s, emb_r,
      W_ih, b_ih, b_hh, W_agg, b_agg, W_last, b_last, W_query, b_query, w_W,
      E1, E2, Hfull, Cq);
  k_match<<<dim3(NB*NSTEP), dim3(128), 0, stream>>>(
      question, q_neighbors, s_neighbors, nselp, mwords);
  k_attn<<<dim3(NB*NSTEP), dim3(128), 0, stream>>>(
      question, qs_table, emb_q, emb_s, b_query, w_W, Hfull, Cq,
      nselp, mwords, out);
}

// Round 3
// 441.221 us; speedup vs baseline: 1.8071x; 1.2119x over previous
//
#include <hip/hip_runtime.h>
#include <stdint.h>

#define NB 32
#define SEQ 128
#define EMB 128
#define NSTEP 127
#define NS 512

__device__ __forceinline__ float ftanh(float x){ float e=__expf(2.f*x); return 1.f-2.f/(e+1.f); }
__device__ __forceinline__ float fsig(float x){ return 1.f/(1.f+__expf(-x)); }
__device__ __forceinline__ float4 ld4(const float* p){ return *(const float4*)p; }

// ---------------------------------------------------------------------------
// Streamed-WT GEMM: out[r,e] = bias[e] + sum_k X[r,k] * WT[k,e]
// X in LDS [16][XS]; WT global row-major [K][NEtot] (pre-transposed weights).
// 256 threads = 32 e-threads (4 e each) x 8 r-threads (2 rows each).
// Per k4: 4 coalesced global b128 (W) + 2 LDS b128 (X) + 32 fma. No barriers.
// ---------------------------------------------------------------------------
#define FMA_COL(acc, xv) \
  acc.x = fmaf(xv.x, w0.x, fmaf(xv.y, w1.x, fmaf(xv.z, w2.x, fmaf(xv.w, w3.x, acc.x)))); \
  acc.y = fmaf(xv.x, w0.y, fmaf(xv.y, w1.y, fmaf(xv.z, w2.y, fmaf(xv.w, w3.y, acc.y)))); \
  acc.z = fmaf(xv.x, w0.z, fmaf(xv.y, w1.z, fmaf(xv.z, w2.z, fmaf(xv.w, w3.z, acc.z)))); \
  acc.w = fmaf(xv.x, w0.w, fmaf(xv.y, w1.w, fmaf(xv.z, w2.w, fmaf(xv.w, w3.w, acc.w))));

template<int K, int XS>
__device__ __forceinline__ void gemm16(const float* __restrict__ WT, int NEtot,
                                       const float* __restrict__ Xl,
                                       const float* __restrict__ bias,
                                       float* __restrict__ outb /*[16][132]*/)
{
  const int tid = threadIdx.x;
  const int et = tid & 31;      // e = et*4
  const int rt = tid >> 5;      // rows rt*2, rt*2+1
  const float* wp = WT + et*4;
  const float* x0 = Xl + (rt*2)*XS;
  const float* x1 = x0 + XS;
  float4 acc0 = {0.f,0.f,0.f,0.f}, acc1 = {0.f,0.f,0.f,0.f};
  float4 w0 = ld4(wp);
  float4 w1 = ld4(wp + NEtot);
  float4 w2 = ld4(wp + 2*NEtot);
  float4 w3 = ld4(wp + 3*NEtot);
  float4 xa = ld4(x0), xb = ld4(x1);
  #pragma unroll 8
  for (int k = 4; k < K; k += 4) {
    const float* wn = wp + (size_t)k*NEtot;
    float4 m0 = ld4(wn);
    float4 m1 = ld4(wn + NEtot);
    float4 m2 = ld4(wn + 2*NEtot);
    float4 m3 = ld4(wn + 3*NEtot);
    float4 ya = ld4(x0 + k), yb = ld4(x1 + k);
    FMA_COL(acc0, xa); FMA_COL(acc1, xb);
    w0=m0; w1=m1; w2=m2; w3=m3; xa=ya; xb=yb;
  }
  FMA_COL(acc0, xa); FMA_COL(acc1, xb);
  float4 bb = ld4(bias + et*4);
  acc0.x+=bb.x; acc0.y+=bb.y; acc0.z+=bb.z; acc0.w+=bb.w;
  acc1.x+=bb.x; acc1.y+=bb.y; acc1.z+=bb.z; acc1.w+=bb.w;
  *(float4*)(outb + (rt*2)*132 + et*4) = acc0;
  *(float4*)(outb + (rt*2+1)*132 + et*4) = acc1;
}
#undef FMA_COL

// ---------------------------------------------------------------------------
// k_T: transpose weights into ws + BIH = b_ih+b_hh + c_pad scalar
// ---------------------------------------------------------------------------
__global__ __launch_bounds__(256) void k_T(
    const float* __restrict__ W_agg, const float* __restrict__ W_last,
    const float* __restrict__ W_query, const float* __restrict__ W_ih,
    const float* __restrict__ b_ih, const float* __restrict__ b_hh,
    const float* __restrict__ b_query, const float* __restrict__ w_W,
    float* __restrict__ WT012, float* __restrict__ WLT, float* __restrict__ WQT,
    float* __restrict__ WIHT, float* __restrict__ BIH, float* __restrict__ CPAD)
{
  const int gid = blockIdx.x*256 + threadIdx.x;
  const int gsz = gridDim.x*256;
  for (int i = gid; i < 49152; i += gsz) {
    int j = i >> 14, rem = i & 16383, k = rem >> 7, e = rem & 127;
    WT012[i] = W_agg[j*16384 + e*128 + k];
  }
  for (int i = gid; i < 16384; i += gsz) {
    int k = i >> 7, e = i & 127;
    WLT[i] = W_last[e*128 + k];
    WQT[i] = W_query[e*128 + k];
  }
  for (int i = gid; i < 131072; i += gsz) {
    int k = i >> 9, e = i & 511;
    WIHT[i] = W_ih[e*256 + k];
  }
  for (int i = gid; i < 512; i += gsz) BIH[i] = b_ih[i] + b_hh[i];
  if (blockIdx.x == 0) {
    __shared__ float red[256];
    float v = (threadIdx.x < 128) ? ftanh(b_query[threadIdx.x]) * w_W[128 + threadIdx.x] : 0.f;
    red[threadIdx.x] = v; __syncthreads();
    #pragma unroll
    for (int s = 128; s > 0; s >>= 1) {
      if (threadIdx.x < s) red[threadIdx.x] += red[threadIdx.x + s];
      __syncthreads();
    }
    if (threadIdx.x == 0) CPAD[0] = red[0];
  }
}

// ---------------------------------------------------------------------------
// k_pre: blocks 0..31: E1[s] (16 s-rows each); blocks 32..351: level-2 rows
// accumulated into G1 via global atomics.
// ---------------------------------------------------------------------------
__global__ __launch_bounds__(256) void k_pre(
    const int* __restrict__ s_neighbors, const int* __restrict__ q_neighbors,
    const float* __restrict__ emb_q, const float* __restrict__ emb_s,
    const float* __restrict__ WT012, const float* __restrict__ b_agg,
    float* __restrict__ E1, float* __restrict__ G1)
{
  __shared__ float XA[16*132];
  __shared__ float XB[16*132];
  __shared__ int idx[160];
  __shared__ int n3[64];
  const int tid = threadIdx.x;
  const int blk = blockIdx.x;
  if (blk < 32) {
    const int s0 = blk*16;
    if (tid < 160) idx[tid] = s_neighbors[s0*10 + tid];
    __syncthreads();
    for (int f = tid; f < 512; f += 256) {
      int r = f >> 5, e4 = (f & 31) << 2;
      float4 a = ld4(emb_s + (size_t)(s0+r)*128 + e4);
      float sx=0,sy=0,sz=0,sw=0;
      #pragma unroll
      for (int jj = 0; jj < 10; ++jj) {
        float4 q = ld4(emb_q + (size_t)idx[r*10+jj]*128 + e4);
        sx+=q.x; sy+=q.y; sz+=q.z; sw+=q.w;
      }
      float4 o; o.x=a.x+0.1f*sx; o.y=a.y+0.1f*sy; o.z=a.z+0.1f*sz; o.w=a.w+0.1f*sw;
      *(float4*)(XA + r*132 + e4) = o;
    }
    __syncthreads();
    gemm16<128,132>(WT012 + 16384, 128, XA, b_agg + 128, XB);
    __syncthreads();
    for (int f = tid; f < 2048; f += 256) {
      int r = f >> 7, e = f & 127;
      E1[(size_t)(s0+r)*128 + e] = ftanh(XB[r*132 + e]);
    }
  } else {
    const int p0 = (blk-32)*16;
    if (tid < 16) idx[tid] = s_neighbors[p0 + tid];
    __syncthreads();
    if (tid < 64) n3[tid] = q_neighbors[(size_t)idx[tid>>2]*4 + (tid&3)];
    __syncthreads();
    for (int f = tid; f < 512; f += 256) {
      int r = f >> 5, e4 = (f & 31) << 2;
      float4 a = ld4(emb_q + (size_t)idx[r]*128 + e4);
      float sx=0,sy=0,sz=0,sw=0;
      #pragma unroll
      for (int k = 0; k < 4; ++k) {
        float4 q = ld4(emb_s + (size_t)n3[r*4+k]*128 + e4);
        sx+=q.x; sy+=q.y; sz+=q.z; sw+=q.w;
      }
      float4 o; o.x=a.x+0.25f*sx; o.y=a.y+0.25f*sy; o.z=a.z+0.25f*sz; o.w=a.w+0.25f*sw;
      *(float4*)(XA + r*132 + e4) = o;
    }
    __syncthreads();
    gemm16<128,132>(WT012 + 32768, 128, XA, b_agg + 256, XB);
    __syncthreads();
    for (int f = tid; f < 2048; f += 256) {
      int r = f >> 7, e = f & 127;
      atomicAdd(&G1[(size_t)((p0+r)/10)*128 + e], ftanh(XB[r*132 + e]));
    }
  }
}

// k_pre2: E2[s] = tanh((0.1*G1[s] + E1[s]) @ W1.T + b1)
__global__ __launch_bounds__(256) void k_pre2(
    const float* __restrict__ E1, const float* __restrict__ G1,
    const float* __restrict__ WT012, const float* __restrict__ b_agg,
    float* __restrict__ E2)
{
  __shared__ float XA[16*132];
  __shared__ float XB[16*132];
  const int tid = threadIdx.x;
  const int s0 = blockIdx.x*16;
  for (int f = tid; f < 2048; f += 256) {
    int r = f >> 7, e = f & 127;
    XA[r*132 + e] = 0.1f*G1[(size_t)(s0+r)*128 + e] + E1[(size_t)(s0+r)*128 + e];
  }
  __syncthreads();
  gemm16<128,132>(WT012 + 16384, 128, XA, b_agg + 128, XB);
  __syncthreads();
  for (int f = tid; f < 2048; f += 256) {
    int r = f >> 7, e = f & 127;
    E2[(size_t)(s0+r)*128 + e] = ftanh(XB[r*132 + e]);
  }
}

// ---------------------------------------------------------------------------
// k_chain: 254 blocks x 16 (b,t)-rows: aggregation chain + LSTM h + Cq
// ---------------------------------------------------------------------------
__global__ __launch_bounds__(256) void k_chain(
    const int* __restrict__ question, const int* __restrict__ response,
    const int* __restrict__ maskp, const int* __restrict__ q_neighbors,
    const float* __restrict__ emb_q, const float* __restrict__ emb_s,
    const float* __restrict__ emb_r,
    const float* __restrict__ WT012, const float* __restrict__ WLT,
    const float* __restrict__ WQT, const float* __restrict__ WIHT,
    const float* __restrict__ BIH,
    const float* __restrict__ b_agg, const float* __restrict__ b_last,
    const float* __restrict__ b_query, const float* __restrict__ w_W,
    const float* __restrict__ E1, const float* __restrict__ E2,
    float* __restrict__ Hfull, float* __restrict__ Cq)
{
  __shared__ float P_[12688];
  __shared__ int qts[16], rts[16], mts[16], n1s[64];
  float* XA = P_;             // [16][132]
  float* XB = P_ + 2112;      // [16][132]
  float* M1 = P_ + 4224;      // [16][128]
  float* M2 = P_ + 6272;      // [16][128]
  float* G3 = P_ + 4224;      // [16][132] overlay (M1/M2 dead by then)
  float* XC = P_ + 8448;      // [16][264]
  float* cq = P_ + 12672;     // [16]

  const int tid = threadIdx.x;
  const int blk = blockIdx.x;

  if (tid < 16) {
    int rid = blk*16 + tid;
    int b = rid / 127, t = rid - b*127;
    qts[tid] = question[b*SEQ + t];
    rts[tid] = response[b*SEQ + t];
    mts[tid] = maskp[b*SEQ + t];
    cq[tid] = 0.f;
  }
  __syncthreads();
  if (tid < 64) n1s[tid] = q_neighbors[(size_t)qts[tid>>2]*4 + (tid&3)];
  __syncthreads();
  // XA = emb_q[qt] + 0.25*sum emb_s[n1]; M1 = 0.25*sum E1[n1]; M2 = 0.25*sum E2[n1]
  for (int f = tid; f < 512; f += 256) {
    int r = f >> 5, e4 = (f & 31) << 2;
    const int* nn = n1s + r*4;
    float4 a = ld4(emb_q + (size_t)qts[r]*128 + e4);
    float s1x=0,s1y=0,s1z=0,s1w=0, s2x=0,s2y=0,s2z=0,s2w=0, s3x=0,s3y=0,s3z=0,s3w=0;
    #pragma unroll
    for (int i = 0; i < 4; ++i) {
      float4 q1 = ld4(emb_s + (size_t)nn[i]*128 + e4);
      float4 q2 = ld4(E1 + (size_t)nn[i]*128 + e4);
      float4 q3 = ld4(E2 + (size_t)nn[i]*128 + e4);
      s1x+=q1.x; s1y+=q1.y; s1z+=q1.z; s1w+=q1.w;
      s2x+=q2.x; s2y+=q2.y; s2z+=q2.z; s2w+=q2.w;
      s3x+=q3.x; s3y+=q3.y; s3z+=q3.z; s3w+=q3.w;
    }
    float4 o; o.x=a.x+0.25f*s1x; o.y=a.y+0.25f*s1y; o.z=a.z+0.25f*s1z; o.w=a.w+0.25f*s1w;
    *(float4*)(XA + r*132 + e4) = o;
    float4 p; p.x=0.25f*s2x; p.y=0.25f*s2y; p.z=0.25f*s2z; p.w=0.25f*s2w;
    *(float4*)(M1 + r*128 + e4) = p;
    float4 u; u.x=0.25f*s3x; u.y=0.25f*s3y; u.z=0.25f*s3z; u.w=0.25f*s3w;
    *(float4*)(M2 + r*128 + e4) = u;
  }
  __syncthreads();
  gemm16<128,132>(WT012, 128, XA, b_agg, XB);          // e0_1 pre-act
  __syncthreads();
  for (int f = tid; f < 2048; f += 256) {
    int r = f >> 7, e = f & 127;
    XB[r*132 + e] = M1[r*128 + e] + ftanh(XB[r*132 + e]);
  }
  __syncthreads();
  gemm16<128,132>(WT012, 128, XB, b_agg, XA);          // e0_2 pre-act
  __syncthreads();
  for (int f = tid; f < 2048; f += 256) {
    int r = f >> 7, e = f & 127;
    XA[r*132 + e] = M2[r*128 + e] + ftanh(XA[r*132 + e]);
  }
  __syncthreads();
  gemm16<128,132>(WT012, 128, XA, b_agg, XB);          // e0_3 pre-act
  __syncthreads();
  for (int f = tid; f < 2048; f += 256) {
    int r = f >> 7, e = f & 127;
    XB[r*132 + e] = ftanh(XB[r*132 + e]);
  }
  __syncthreads();
  gemm16<128,132>(WLT, 128, XB, b_last, XA);           // agg pre-act
  __syncthreads();
  for (int f = tid; f < 2048; f += 256) {
    int r = f >> 7, e = f & 127;
    float agg = ftanh(XA[r*132 + e]);
    XC[r*264 + e] = (mts[r] == 1) ? agg : emb_q[(size_t)qts[r]*128 + e];
    XC[r*264 + 128 + e] = emb_r[rts[r]*128 + e];
  }
  __syncthreads();
  gemm16<256,264>(WIHT,       512, XC, BIH,       XA); // gi
  gemm16<256,264>(WIHT + 256, 512, XC, BIH + 256, XB); // gg
  gemm16<256,264>(WIHT + 384, 512, XC, BIH + 384, G3); // go
  __syncthreads();
  for (int f = tid; f < 2048; f += 256) {
    int r = f >> 7, e = f & 127;
    float gi = XA[r*132 + e], gg = XB[r*132 + e], go = G3[r*132 + e];
    float h = fsig(go) * ftanh(fsig(gi) * ftanh(gg));
    XC[r*264 + e] = h;
    Hfull[(size_t)(blk*16 + r)*128 + e] = h;
  }
  __syncthreads();
  gemm16<128,264>(WQT, 128, XC, b_query, XA);          // c pre-act
  __syncthreads();
  {
    const int et = tid & 31, rt = tid >> 5;
    const float* wk = w_W + 128 + et*4;
    float4 wv = ld4(wk);
    #pragma unroll
    for (int rr = 0; rr < 2; ++rr) {
      int r = rt*2 + rr;
      const float* o = XA + r*132 + et*4;
      float s = ftanh(o[0])*wv.x + ftanh(o[1])*wv.y + ftanh(o[2])*wv.z + ftanh(o[3])*wv.w;
      atomicAdd(&cq[r], s);
    }
  }
  __syncthreads();
  if (tid < 16) Cq[blk*16 + tid] = cq[tid];
}

// ---------------------------------------------------------------------------
// k_match_t: one block per t: masks + nsel for all b, and Pmax[t]
// ---------------------------------------------------------------------------
__global__ __launch_bounds__(128) void k_match_t(
    const int* __restrict__ question, const int* __restrict__ q_neighbors,
    const int* __restrict__ s_neighbors,
    int* __restrict__ nsel, unsigned long long* __restrict__ mwords,
    float* __restrict__ Pmax)
{
  __shared__ int nq[4];
  __shared__ int qr[40];
  __shared__ unsigned long long wv[2];
  const int tid = threadIdx.x;
  const int t = blockIdx.x;
  int pm = 0;
  for (int b = 0; b < NB; ++b) {
    const int q_next = question[b*SEQ + t + 1];
    if (tid < 4) nq[tid] = q_neighbors[(size_t)q_next*4 + tid];
    __syncthreads();
    if (tid < 40) qr[tid] = s_neighbors[(size_t)nq[tid/10]*10 + tid%10];
    __syncthreads();
    bool pred = false;
    if (tid < t) {
      int qp = question[b*SEQ + tid];
      #pragma unroll 8
      for (int i = 0; i < 40; ++i) pred |= (qp == qr[i]);
    }
    unsigned long long bal = __ballot(pred);
    if ((tid & 63) == 0) wv[tid >> 6] = bal;
    __syncthreads();
    if (tid == 0) {
      mwords[((size_t)b*NSTEP + t)*2 + 0] = wv[0];
      mwords[((size_t)b*NSTEP + t)*2 + 1] = wv[1];
      int ns = __popcll(wv[0]) + __popcll(wv[1]);
      nsel[b*NSTEP + t] = ns;
      pm = max(pm, ns);
    }
    __syncthreads();
  }
  if (tid == 0) Pmax[t] = (float)pm;
}

__device__ __forceinline__ float bsum128(float v, float* red) {
  const int tid = threadIdx.x;
  __syncthreads();
  red[tid] = v;
  __syncthreads();
  #pragma unroll
  for (int s = 64; s > 0; s >>= 1) {
    if (tid < s) red[tid] += red[tid + s];
    __syncthreads();
  }
  return red[0];
}
__device__ __forceinline__ float bmax128(float v, float* red) {
  const int tid = threadIdx.x;
  __syncthreads();
  red[tid] = v;
  __syncthreads();
  #pragma unroll
  for (int s = 64; s > 0; s >>= 1) {
    if (tid < s) red[tid] = fmaxf(red[tid], red[tid + s]);
    __syncthreads();
  }
  return red[0];
}

// ---------------------------------------------------------------------------
// k_attn: collapsed attention (a[q] cancels across the softmax), y -> out
// ---------------------------------------------------------------------------
__global__ __launch_bounds__(128) void k_attn(
    const int* __restrict__ question, const float* __restrict__ qs_table,
    const float* __restrict__ emb_q, const float* __restrict__ emb_s,
    const float* __restrict__ CPAD,
    const float* __restrict__ Hfull, const float* __restrict__ Cq,
    const int* __restrict__ nsel, const unsigned long long* __restrict__ mwords,
    const float* __restrict__ Pmax, float* __restrict__ out)
{
  __shared__ float red[128];
  __shared__ float us[128];
  __shared__ int cols[8];
  __shared__ int cnt;
  const int tid = threadIdx.x;
  const int bid = blockIdx.x;
  const int b = bid / NSTEP, t = bid % NSTEP;
  const size_t bt = (size_t)b*NSTEP + t;
  const int q_next = question[b*SEQ + t + 1];

  if (tid == 0) cnt = 0;
  __syncthreads();
  #pragma unroll
  for (int m = 0; m < 4; ++m) {
    int c = tid + 128*m;
    float v = qs_table[(size_t)q_next*NS + c];
    if (v > 0.f) {
      int p = atomicAdd(&cnt, 1);
      if (p < 8) cols[p] = c;
    }
  }
  __syncthreads();
  const int nc = min(cnt, 4);
  {
    float ue = emb_q[(size_t)q_next*EMB + tid];
    for (int i = 0; i < nc; ++i) ue += emb_s[(size_t)cols[i]*EMB + tid];
    us[tid] = ue;
  }
  const float c_pad = CPAD[0];
  const float P = Pmax[t] - (float)nsel[bt];

  const unsigned long long w0 = mwords[bt*2 + 0];
  const unsigned long long w1 = mwords[bt*2 + 1];
  const bool matched = (tid < 64) ? ((w0 >> tid) & 1ull)
                                  : ((w1 >> (tid - 64)) & 1ull);
  const float c_cur = Cq[bt];
  float Cp = 0.f;
  if (matched) Cp = (tid == 0) ? c_pad : Cq[(size_t)b*NSTEP + tid];
  float Mh = bmax128(matched ? Cp : -3.0e38f, red);
  float M = fmaxf(fmaxf(Mh, c_cur), c_pad);
  float wgt = matched ? __expf(Cp - M) : 0.f;
  float Sexp = bsum128(wgt, red);
  float dotp = 0.f;
  if (matched && tid >= 1) {  // p=0 history row is zeros
    const float* hp = Hfull + ((size_t)b*NSTEP + tid)*EMB;
    float s = 0.f;
    for (int e = 0; e < 128; e += 4) {
      float4 h4 = ld4(hp + e);
      s = fmaf(us[e],h4.x, fmaf(us[e+1],h4.y, fmaf(us[e+2],h4.z, fmaf(us[e+3],h4.w, s))));
    }
    dotp = s;
  }
  float Snum = bsum128(wgt * dotp, red);
  float gc = bsum128(us[tid] * Hfull[bt*EMB + tid], red);
  float Ec = __expf(c_cur - M), Ep = __expf(c_pad - M);
  float D = Sexp + Ec + P * Ep;
  float numt = Snum + Ec * gc;
  if (tid == 0) {
    out[b*SEQ + t + 1] = fsig(numt / D);
    if (t == 0) out[b*SEQ] = 0.5f;
  }
}

extern "C" void kernel_launch(void* const* d_in, const int* in_sizes, int n_in,
                              void* d_out, int out_size, void* d_ws, size_t ws_size,
                              hipStream_t stream) {
  const int* question    = (const int*)d_in[0];
  const int* response    = (const int*)d_in[1];
  const int* maskp       = (const int*)d_in[2];
  const int* q_neighbors = (const int*)d_in[3];
  const int* s_neighbors = (const int*)d_in[4];
  const float* qs_table  = (const float*)d_in[5];
  const float* emb_q     = (const float*)d_in[6];
  const float* emb_s     = (const float*)d_in[7];
  const float* emb_r     = (const float*)d_in[8];
  const float* W_ih      = (const float*)d_in[9];
  const float* b_ih      = (const float*)d_in[10];
  const float* b_hh      = (const float*)d_in[11];
  const float* W_agg     = (const float*)d_in[12];
  const float* b_agg     = (const float*)d_in[13];
  const float* W_last    = (const float*)d_in[14];
  const float* b_last    = (const float*)d_in[15];
  const float* W_query   = (const float*)d_in[16];
  const float* b_query   = (const float*)d_in[17];
  // d_in[18] W_key, d_in[19] b_key, d_in[21] b_W: no effect (a[q] cancels)
  const float* w_W       = (const float*)d_in[20];
  float* out = (float*)d_out;

  float* ws = (float*)d_ws;
  float* WT012 = ws;                    // 49152 (WT0|WT1|WT2)
  float* WLT   = ws + 49152;            // 16384
  float* WQT   = ws + 65536;            // 16384
  float* WIHT  = ws + 81920;            // 131072  [256][512]
  float* BIH   = ws + 212992;           // 512
  float* CPAD  = ws + 213504;           // 16
  float* E1    = ws + 213520;           // 65536
  float* G1    = ws + 279056;           // 65536
  float* E2    = ws + 344592;           // 65536
  float* Hfull = ws + 410128;           // 4064*128 = 520192
  float* Cq    = ws + 930320;           // 4064
  float* Pmax  = ws + 934384;           // 128
  int*   nselp = (int*)(ws + 934512);   // 4064
  unsigned long long* mwords =
      (unsigned long long*)(((uintptr_t)(ws + 938576) + 15) & ~(uintptr_t)15);

  hipMemsetAsync(G1, 0, 65536*sizeof(float), stream);
  k_T<<<dim3(64), dim3(256), 0, stream>>>(
      W_agg, W_last, W_query, W_ih, b_ih, b_hh, b_query, w_W,
      WT012, WLT, WQT, WIHT, BIH, CPAD);
  k_pre<<<dim3(352), dim3(256), 0, stream>>>(
      s_neighbors, q_neighbors, emb_q, emb_s, WT012, b_agg, E1, G1);
  k_pre2<<<dim3(32), dim3(256), 0, stream>>>(E1, G1, WT012, b_agg, E2);
  k_chain<<<dim3(254), dim3(256), 0, stream>>>(
      question, response, maskp, q_neighbors, emb_q, emb_s, emb_r,
      WT012, WLT, WQT, WIHT, BIH, b_agg, b_last, b_query, w_W,
      E1, E2, Hfull, Cq);
  k_match_t<<<dim3(NSTEP), dim3(128), 0, stream>>>(
      question, q_neighbors, s_neighbors, nselp, mwords, Pmax);
  k_attn<<<dim3(NB*NSTEP), dim3(128), 0, stream>>>(
      question, qs_table, emb_q, emb_s, CPAD, Hfull, Cq,
      nselp, mwords, Pmax, out);
}